// Round 2
// baseline (352.172 us; speedup 1.0000x reference)
//
#include <hip/hip_runtime.h>
#include <hip/hip_bf16.h>

// EdgeConv, CSR-by-dst, bf16 intermediates:
//   abf[n] = bf16(h@W1[0:64]); bsf[n] = bf16(h@W1[64:128]+b1)
//   acc[n] = sum_{e:dst=n} relu(abf[src] + bsf[n] + e*w128)   (wave/node, lane=feat)
//   out[n] = acc[n] @ W2 + cnt[n]*b2                          (fused readlane matvec)
// R2: precompute rewritten latency-proof: __launch_bounds__(256,2) so x4[16]+acc
//     stay in VGPRs (old build: VGPR=60 -> spills -> 97% stall, VALUBusy 11%);
//     W1 rows forced down the VECTOR load path (opaque VGPR zero) -> L1-broadcast
//     dwordx4 with deep vmcnt pipelining instead of SGPR-starved s_loads.
//     Fill path single-pass: rank[i] captured from count's atomicAdd -> scatter
//     is non-atomic, no 8x-replicated edge sweep, no cursor array.

#define NSH 8

// ---------------- count + rank ----------------
__global__ void count_kernel(const int* __restrict__ dst, int* __restrict__ counts,
                             int* __restrict__ rank, int n_edges) {
    int i = blockIdx.x * blockDim.x + threadIdx.x;
    if (i < n_edges) rank[i] = atomicAdd(&counts[dst[i]], 1);
}

// ---------------- per-shard totals (block = 256 nodes, single shard) ----------------
__global__ __launch_bounds__(256) void shard_sum_kernel(const int* __restrict__ counts,
                                                        int* __restrict__ shardTotal,
                                                        int n, int shsz) {
    __shared__ int ws[4];
    const int i    = blockIdx.x * 256 + threadIdx.x;
    const int lane = threadIdx.x & 63;
    const int wv   = threadIdx.x >> 6;
    int c = (i < n) ? counts[i] : 0;
    #pragma unroll
    for (int d = 1; d < 64; d <<= 1) c += __shfl_xor(c, d, 64);
    if (lane == 0) ws[wv] = c;
    __syncthreads();
    if (threadIdx.x == 0)
        atomicAdd(&shardTotal[(blockIdx.x * 256) / shsz], ws[0] + ws[1] + ws[2] + ws[3]);
}

// ---------------- shard-contiguous offset allocation ----------------
__global__ __launch_bounds__(256) void alloc_offs_kernel(const int* __restrict__ counts,
                                                         const int* __restrict__ shardTotal,
                                                         int* __restrict__ shard_cursor,
                                                         int* __restrict__ offs, int n, int shsz) {
    __shared__ int wsum[4];
    const int i     = blockIdx.x * 256 + threadIdx.x;
    const int lane  = threadIdx.x & 63;
    const int wv    = threadIdx.x >> 6;
    const int shard = (blockIdx.x * 256) / shsz;   // uniform (shsz % 256 == 0)

    const int c = (i < n) ? counts[i] : 0;
    int incl = c;
    #pragma unroll
    for (int d = 1; d < 64; d <<= 1) {
        int v = __shfl_up(incl, d, 64);
        if (lane >= d) incl += v;
    }
    const int excl = incl - c;
    if (lane == 63) wsum[wv] = incl;
    __syncthreads();
    if (threadIdx.x == 0) {
        int base0 = 0;
        #pragma unroll
        for (int t = 0; t < NSH; ++t) if (t < shard) base0 += shardTotal[t];
        const int s0 = wsum[0], s1 = wsum[1], s2 = wsum[2], s3 = wsum[3];
        const int b = base0 + atomicAdd(&shard_cursor[shard], s0 + s1 + s2 + s3);
        wsum[0] = b; wsum[1] = b + s0; wsum[2] = b + s0 + s1; wsum[3] = b + s0 + s1 + s2;
    }
    __syncthreads();
    if (i < n) offs[i] = wsum[wv] + excl;
}

// ---------------- single-pass non-atomic fill ----------------
__global__ void fill_kernel(const int* __restrict__ dst, const int* __restrict__ src,
                            const float* __restrict__ e,
                            const int* __restrict__ offs, const int* __restrict__ rank,
                            int2* __restrict__ meta, int n_edges) {
    const int i = blockIdx.x * blockDim.x + threadIdx.x;
    if (i >= n_edges) return;
    const int d = dst[i];
    meta[offs[d] + rank[i]] = make_int2(src[i], __float_as_int(e[i]));
}

// ---------------- abf = bf16(h@W1t), bsf = bf16(h@W1b + b1) ----------------
__global__ __launch_bounds__(256, 2) void precompute_ab_kernel(
    const float* __restrict__ h, const float* __restrict__ W1, const float* __restrict__ b1,
    unsigned short* __restrict__ abf, unsigned short* __restrict__ bsf, int n_nodes)
{
    const int lane = threadIdx.x & 63;
    const int wv   = threadIdx.x >> 6;
    const int j0   = __builtin_amdgcn_readfirstlane((wv & 1) << 5);  // wave-uniform 0/32
    const int n    = blockIdx.x * 128 + ((wv >> 1) << 6) + lane;
    if (n >= n_nodes) return;

    // opaque VGPR zero: forces the (lane-uniform) weight addresses down the
    // vector-memory path -> global_load_dwordx4, L1 line broadcast, deep vmcnt queue
    int z;
    asm("v_mov_b32 %0, 0" : "=v"(z));

    float4 x4[16];
    const float4* hp = reinterpret_cast<const float4*>(h + (size_t)n * 64);
    #pragma unroll
    for (int k4 = 0; k4 < 16; ++k4) x4[k4] = hp[k4];

    const float* __restrict__ Wv = W1 + j0 + z;

    // ---- pass A: av = h @ W1[0:64, j0:j0+32] ----
    {
        float av[32];
        #pragma unroll
        for (int j = 0; j < 32; ++j) av[j] = 0.f;

        #pragma unroll
        for (int k4 = 0; k4 < 16; ++k4) {
            const float xv[4] = { x4[k4].x, x4[k4].y, x4[k4].z, x4[k4].w };
            #pragma unroll
            for (int r = 0; r < 4; ++r) {
                const float4* wr = reinterpret_cast<const float4*>(Wv + (size_t)(4 * k4 + r) * 64);
                float4 wq[8];
                #pragma unroll
                for (int q = 0; q < 8; ++q) wq[q] = wr[q];
                #pragma unroll
                for (int q = 0; q < 8; ++q) {
                    av[4 * q + 0] = fmaf(xv[r], wq[q].x, av[4 * q + 0]);
                    av[4 * q + 1] = fmaf(xv[r], wq[q].y, av[4 * q + 1]);
                    av[4 * q + 2] = fmaf(xv[r], wq[q].z, av[4 * q + 2]);
                    av[4 * q + 3] = fmaf(xv[r], wq[q].w, av[4 * q + 3]);
                }
            }
        }

        uint pk[16];
        #pragma unroll
        for (int q = 0; q < 16; ++q) {
            __hip_bfloat16 l0 = __float2bfloat16(av[2 * q]);
            __hip_bfloat16 l1 = __float2bfloat16(av[2 * q + 1]);
            pk[q] = ((uint)*reinterpret_cast<unsigned short*>(&l1) << 16) |
                    *reinterpret_cast<unsigned short*>(&l0);
        }
        uint4* p4 = reinterpret_cast<uint4*>(abf + (size_t)n * 64 + j0);
        #pragma unroll
        for (int q = 0; q < 4; ++q)
            p4[q] = make_uint4(pk[4 * q], pk[4 * q + 1], pk[4 * q + 2], pk[4 * q + 3]);
    }

    // ---- pass B: bv = h @ W1[64:128, j0:j0+32] + b1 ----
    {
        float bv[32];
        #pragma unroll
        for (int j = 0; j < 32; ++j) bv[j] = b1[j0 + j];

        #pragma unroll
        for (int k4 = 0; k4 < 16; ++k4) {
            const float xv[4] = { x4[k4].x, x4[k4].y, x4[k4].z, x4[k4].w };
            #pragma unroll
            for (int r = 0; r < 4; ++r) {
                const float4* wr =
                    reinterpret_cast<const float4*>(Wv + (size_t)(64 + 4 * k4 + r) * 64);
                float4 wq[8];
                #pragma unroll
                for (int q = 0; q < 8; ++q) wq[q] = wr[q];
                #pragma unroll
                for (int q = 0; q < 8; ++q) {
                    bv[4 * q + 0] = fmaf(xv[r], wq[q].x, bv[4 * q + 0]);
                    bv[4 * q + 1] = fmaf(xv[r], wq[q].y, bv[4 * q + 1]);
                    bv[4 * q + 2] = fmaf(xv[r], wq[q].z, bv[4 * q + 2]);
                    bv[4 * q + 3] = fmaf(xv[r], wq[q].w, bv[4 * q + 3]);
                }
            }
        }

        uint pk[16];
        #pragma unroll
        for (int q = 0; q < 16; ++q) {
            __hip_bfloat16 l0 = __float2bfloat16(bv[2 * q]);
            __hip_bfloat16 l1 = __float2bfloat16(bv[2 * q + 1]);
            pk[q] = ((uint)*reinterpret_cast<unsigned short*>(&l1) << 16) |
                    *reinterpret_cast<unsigned short*>(&l0);
        }
        uint4* p4 = reinterpret_cast<uint4*>(bsf + (size_t)n * 64 + j0);
        #pragma unroll
        for (int q = 0; q < 4; ++q)
            p4[q] = make_uint4(pk[4 * q], pk[4 * q + 1], pk[4 * q + 2], pk[4 * q + 3]);
    }
}

// ---------------- accum: wave/node, lane=feat, register-meta + depth-8 prefetch ----------------
__global__ __launch_bounds__(256) void node_accum_kernel(
    const unsigned short* __restrict__ abf, const unsigned short* __restrict__ bsf,
    const float* __restrict__ W1, const float* __restrict__ W2, const float* __restrict__ b2,
    const int* __restrict__ offs, const int* __restrict__ counts,
    const int2* __restrict__ meta, float* __restrict__ out, int n_nodes)
{
    const int lane = threadIdx.x & 63;
    const int wv   = __builtin_amdgcn_readfirstlane(threadIdx.x >> 6);
    const int n    = blockIdx.x * 4 + wv;          // wave-uniform node id
    if (n >= n_nodes) return;

    const float basel = __uint_as_float((uint)bsf[(size_t)n * 64 + lane] << 16);
    const float w128l = W1[(size_t)128 * 64 + lane];
    float acc = 0.f;

    const int beg = offs[n];     // s_load (n uniform)
    const int np  = counts[n];   // s_load

    // chunks of <=64 edges: meta staged into registers by ONE lane-parallel load,
    // per-edge src/e extracted with v_readlane (no memory on the gather-addr path)
    for (int c0 = 0; c0 < np; c0 += 64) {
        const int cn = min(np - c0, 64);

        int mx = 0, my = 0;
        if (lane < cn) {
            const int2 m = meta[beg + c0 + lane];   // 512B coalesced, once per chunk
            mx = m.x; my = m.y;
        }

        // pipeline slots hold the RAW zext ushort; <<16 happens at consume time
        uint x0=0,x1=0,x2=0,x3=0,x4=0,x5=0,x6=0,x7=0;

        auto ld = [&](int j, uint& x) {
            const int s = __builtin_amdgcn_readlane(mx, j);        // uniform src id
            x = (uint)abf[(size_t)s * 64 + lane];                  // saddr gather, 128B/wave
        };
        auto step = [&](int j, uint xr) {
            const float ev = __uint_as_float((uint)__builtin_amdgcn_readlane(my, j));
            const float xv = __uint_as_float(xr << 16);
            acc += fmaxf(fmaf(ev, w128l, basel) + xv, 0.f);
        };

        if (cn > 0) ld(0, x0);
        if (cn > 1) ld(1, x1);
        if (cn > 2) ld(2, x2);
        if (cn > 3) ld(3, x3);
        if (cn > 4) ld(4, x4);
        if (cn > 5) ld(5, x5);
        if (cn > 6) ld(6, x6);
        if (cn > 7) ld(7, x7);

        int i = 0;
        while (i + 16 <= cn) {
            step(i + 0, x0); ld(i + 8,  x0);
            step(i + 1, x1); ld(i + 9,  x1);
            step(i + 2, x2); ld(i + 10, x2);
            step(i + 3, x3); ld(i + 11, x3);
            step(i + 4, x4); ld(i + 12, x4);
            step(i + 5, x5); ld(i + 13, x5);
            step(i + 6, x6); ld(i + 14, x6);
            step(i + 7, x7); ld(i + 15, x7);
            i += 8;
        }
        const int r = cn - i;   // 0..15
        if (r > 0)  { step(i + 0, x0); }  if (r > 8)  { ld(i + 8,  x0); }
        if (r > 1)  { step(i + 1, x1); }  if (r > 9)  { ld(i + 9,  x1); }
        if (r > 2)  { step(i + 2, x2); }  if (r > 10) { ld(i + 10, x2); }
        if (r > 3)  { step(i + 3, x3); }  if (r > 11) { ld(i + 11, x3); }
        if (r > 4)  { step(i + 4, x4); }  if (r > 12) { ld(i + 12, x4); }
        if (r > 5)  { step(i + 5, x5); }  if (r > 13) { ld(i + 13, x5); }
        if (r > 6)  { step(i + 6, x6); }  if (r > 14) { ld(i + 14, x6); }
        if (r > 7)  { step(i + 7, x7); }
        if (r > 8)  { step(i + 8,  x0); }
        if (r > 9)  { step(i + 9,  x1); }
        if (r > 10) { step(i + 10, x2); }
        if (r > 11) { step(i + 11, x3); }
        if (r > 12) { step(i + 12, x4); }
        if (r > 13) { step(i + 13, x5); }
        if (r > 14) { step(i + 14, x6); }
    }

    // fused epilogue: out[n][lane] = sum_j acc_j * W2[j][lane] + np*b2[lane]
    float o = (float)np * b2[lane];
    #pragma unroll
    for (int j = 0; j < 64; ++j) {
        const float aj = __shfl(acc, j, 64);               // v_readlane
        o = fmaf(aj, W2[(size_t)j * 64 + lane], o);        // coalesced, L1-hot
    }
    out[(size_t)n * 64 + lane] = o;
}

extern "C" void kernel_launch(void* const* d_in, const int* in_sizes, int n_in,
                              void* d_out, int out_size, void* d_ws, size_t ws_size,
                              hipStream_t stream) {
    const float* h  = (const float*)d_in[0];
    const float* e  = (const float*)d_in[1];
    const int* src  = (const int*)d_in[2];
    const int* dst  = (const int*)d_in[3];
    const float* W1 = (const float*)d_in[4];
    const float* b1 = (const float*)d_in[5];
    const float* W2 = (const float*)d_in[6];
    const float* b2 = (const float*)d_in[7];
    float* out = (float*)d_out;

    const int n_edges = in_sizes[2];
    const int N = in_sizes[0] / 64;

    // shard size: multiple of 256 so every 256-node block sits in one shard
    const int shsz = ((N + NSH * 256 - 1) / (NSH * 256)) * 256;   // 12544 for N=100000

    // ws: [counts N | shardTotal 8 | shard_cursor 8 | offs N | rank E] ints,
    //     [meta 2E] ints, [abf 64N ushort], [bsf 64N ushort]
    int* counts       = (int*)d_ws;
    int* shardTotal   = counts + N;
    int* shard_cursor = shardTotal + NSH;
    int* offs         = shard_cursor + NSH;
    int* rank         = offs + N;
    int2* meta        = (int2*)(rank + n_edges);
    unsigned short* abf = (unsigned short*)(meta + n_edges);
    unsigned short* bsf = abf + (size_t)64 * N;

    // zero all atomically-updated counters every call (counts + shard totals/cursors)
    hipMemsetAsync(counts, 0, ((size_t)N + 2 * NSH) * sizeof(int), stream);

    const int eb = (n_edges + 255) / 256;
    const int nb = (N + 255) / 256;
    const int pg = (N + 127) / 128;

    precompute_ab_kernel<<<pg, 256, 0, stream>>>(h, W1, b1, abf, bsf, N);
    count_kernel<<<eb, 256, 0, stream>>>(dst, counts, rank, n_edges);
    shard_sum_kernel<<<nb, 256, 0, stream>>>(counts, shardTotal, N, shsz);
    alloc_offs_kernel<<<nb, 256, 0, stream>>>(counts, shardTotal, shard_cursor, offs, N, shsz);
    fill_kernel<<<eb, 256, 0, stream>>>(dst, src, e, offs, rank, meta, n_edges);
    node_accum_kernel<<<(N + 3) / 4, 256, 0, stream>>>(abf, bsf, W1, W2, b2,
                                                       offs, counts, meta, out, N);
}

// Round 3
// 228.271 us; speedup vs baseline: 1.5428x; 1.5428x over previous
//
#include <hip/hip_runtime.h>
#include <hip/hip_bf16.h>

// EdgeConv, CSR-by-dst, bf16 intermediates:
//   abf[n] = bf16(h@W1[0:64]); bsf[n] = bf16(h@W1[64:128]+b1)
//   acc[n] = sum_{e:dst=n} relu(abf[src] + bsf[n] + e*w128)   (wave/node, lane=feat)
//   out[n] = acc[n] @ W2 + cnt[n]*b2                          (fused readlane matvec)
// R3 precompute: lane = OUTPUT feature; each lane keeps its W1 column (128 floats)
//   in VGPRs, loaded once per block. h rows staged tile-wise into LDS via
//   global_load_lds (deep vmcnt queue hides HBM latency), consumed as wave-uniform
//   broadcast ds_read_b128 + 128 fma/node. R2's spill disaster (VGPR cap 128 ->
//   109MB scratch writes) is structurally impossible here: only 128 wreg + scalars.
// Fill path single-pass (R2): rank[i] from count's atomicAdd -> non-atomic scatter.

#define NSH 8
#define PRE_NPB 128   // nodes per block (2 tiles of 64)

typedef unsigned int u32;

__device__ __forceinline__ void gload_lds16(const float* g, float* l) {
    __builtin_amdgcn_global_load_lds(
        (const __attribute__((address_space(1))) u32*)g,
        (__attribute__((address_space(3))) u32*)l,
        16, 0, 0);
}

// ---------------- count + rank ----------------
__global__ void count_kernel(const int* __restrict__ dst, int* __restrict__ counts,
                             int* __restrict__ rank, int n_edges) {
    int i = blockIdx.x * blockDim.x + threadIdx.x;
    if (i < n_edges) rank[i] = atomicAdd(&counts[dst[i]], 1);
}

// ---------------- per-shard totals (block = 256 nodes, single shard) ----------------
__global__ __launch_bounds__(256) void shard_sum_kernel(const int* __restrict__ counts,
                                                        int* __restrict__ shardTotal,
                                                        int n, int shsz) {
    __shared__ int ws[4];
    const int i    = blockIdx.x * 256 + threadIdx.x;
    const int lane = threadIdx.x & 63;
    const int wv   = threadIdx.x >> 6;
    int c = (i < n) ? counts[i] : 0;
    #pragma unroll
    for (int d = 1; d < 64; d <<= 1) c += __shfl_xor(c, d, 64);
    if (lane == 0) ws[wv] = c;
    __syncthreads();
    if (threadIdx.x == 0)
        atomicAdd(&shardTotal[(blockIdx.x * 256) / shsz], ws[0] + ws[1] + ws[2] + ws[3]);
}

// ---------------- shard-contiguous offset allocation ----------------
__global__ __launch_bounds__(256) void alloc_offs_kernel(const int* __restrict__ counts,
                                                         const int* __restrict__ shardTotal,
                                                         int* __restrict__ shard_cursor,
                                                         int* __restrict__ offs, int n, int shsz) {
    __shared__ int wsum[4];
    const int i     = blockIdx.x * 256 + threadIdx.x;
    const int lane  = threadIdx.x & 63;
    const int wv    = threadIdx.x >> 6;
    const int shard = (blockIdx.x * 256) / shsz;   // uniform (shsz % 256 == 0)

    const int c = (i < n) ? counts[i] : 0;
    int incl = c;
    #pragma unroll
    for (int d = 1; d < 64; d <<= 1) {
        int v = __shfl_up(incl, d, 64);
        if (lane >= d) incl += v;
    }
    const int excl = incl - c;
    if (lane == 63) wsum[wv] = incl;
    __syncthreads();
    if (threadIdx.x == 0) {
        int base0 = 0;
        #pragma unroll
        for (int t = 0; t < NSH; ++t) if (t < shard) base0 += shardTotal[t];
        const int s0 = wsum[0], s1 = wsum[1], s2 = wsum[2], s3 = wsum[3];
        const int b = base0 + atomicAdd(&shard_cursor[shard], s0 + s1 + s2 + s3);
        wsum[0] = b; wsum[1] = b + s0; wsum[2] = b + s0 + s1; wsum[3] = b + s0 + s1 + s2;
    }
    __syncthreads();
    if (i < n) offs[i] = wsum[wv] + excl;
}

// ---------------- single-pass non-atomic fill ----------------
__global__ void fill_kernel(const int* __restrict__ dst, const int* __restrict__ src,
                            const float* __restrict__ e,
                            const int* __restrict__ offs, const int* __restrict__ rank,
                            int2* __restrict__ meta, int n_edges) {
    const int i = blockIdx.x * blockDim.x + threadIdx.x;
    if (i >= n_edges) return;
    const int d = dst[i];
    meta[offs[d] + rank[i]] = make_int2(src[i], __float_as_int(e[i]));
}

// ---------------- abf = bf16(h@W1t), bsf = bf16(h@W1b + b1) ----------------
// lane = output feature j; wreg[k] = W1[k][j] held in VGPRs; h tiles via LDS.
__global__ __launch_bounds__(256, 3) void precompute_ab_kernel(
    const float* __restrict__ h, const float* __restrict__ W1, const float* __restrict__ b1,
    unsigned short* __restrict__ abf, unsigned short* __restrict__ bsf, int n_nodes)
{
    __shared__ float hbuf[2][64 * 64];             // 2 x 16KB tiles (64 nodes each)
    const int lane = threadIdx.x & 63;
    const int wv   = threadIdx.x >> 6;

    const int base = blockIdx.x * PRE_NPB;
    if (base >= n_nodes) return;
    const int nrem   = n_nodes - base;
    const int ntiles = (nrem >= PRE_NPB) ? (PRE_NPB / 64) : ((nrem + 63) >> 6);

    // one-time per-block: whole W1 column for this lane into VGPRs (L2-hot)
    float wreg[128];
    #pragma unroll
    for (int k = 0; k < 128; ++k) wreg[k] = W1[(size_t)k * 64 + lane];
    const float b1l = b1[lane];

    // stage tile t (64 nodes = 16KB) into hbuf[buf]
    auto stage = [&](int buf, int node_base) {
        if (node_base + 64 <= n_nodes) {
            // fast path: 16 x 1KB global_load_lds, 4 per wave, linear dest
            const float* gsrc = h + (size_t)node_base * 64;
            #pragma unroll
            for (int q = 0; q < 4; ++q) {
                const int c = wv * 4 + q;          // 1KB chunk id
                gload_lds16(gsrc + c * 256 + lane * 4, &hbuf[buf][c * 256]);
            }
        } else {
            // guarded tail: reg-staged float4 with bounds check
            #pragma unroll
            for (int q = 0; q < 4; ++q) {
                const int f4 = threadIdx.x + 256 * q;            // float4 idx in tile
                const long gf = (long)node_base * 16 + f4;       // global float4 idx
                float4 v = make_float4(0.f, 0.f, 0.f, 0.f);
                if (gf < (long)n_nodes * 16)
                    v = reinterpret_cast<const float4*>(h)[gf];
                reinterpret_cast<float4*>(hbuf[buf])[f4] = v;
            }
        }
    };

    // consume tile: wave wv handles nodes [wv*16, wv*16+16) of the tile
    auto consume = [&](int buf, int node_base) {
        #pragma unroll 2
        for (int i = 0; i < 16; ++i) {
            const int ln = wv * 16 + i;            // node-in-tile, wave-uniform
            const int n  = node_base + ln;
            if (n < n_nodes) {
                const float4* hr = reinterpret_cast<const float4*>(&hbuf[buf][ln * 64]);
                float av = 0.f, bv = b1l;
                #pragma unroll
                for (int k4 = 0; k4 < 16; ++k4) {
                    const float4 h4 = hr[k4];      // ds_read_b128, uniform broadcast
                    av = fmaf(h4.x, wreg[4 * k4 + 0], av);
                    bv = fmaf(h4.x, wreg[64 + 4 * k4 + 0], bv);
                    av = fmaf(h4.y, wreg[4 * k4 + 1], av);
                    bv = fmaf(h4.y, wreg[64 + 4 * k4 + 1], bv);
                    av = fmaf(h4.z, wreg[4 * k4 + 2], av);
                    bv = fmaf(h4.z, wreg[64 + 4 * k4 + 2], bv);
                    av = fmaf(h4.w, wreg[4 * k4 + 3], av);
                    bv = fmaf(h4.w, wreg[64 + 4 * k4 + 3], bv);
                }
                __hip_bfloat16 ab = __float2bfloat16(av);
                __hip_bfloat16 bb = __float2bfloat16(bv);
                abf[(size_t)n * 64 + lane] = *reinterpret_cast<unsigned short*>(&ab);
                bsf[(size_t)n * 64 + lane] = *reinterpret_cast<unsigned short*>(&bb);
            }
        }
    };

    stage(0, base);
    __syncthreads();                               // tile0 resident
    for (int t = 0; t < ntiles; ++t) {
        if (t + 1 < ntiles) stage((t + 1) & 1, base + (t + 1) * 64);  // prefetch next
        consume(t & 1, base + t * 64);             // compute current (covers latency)
        __syncthreads();                           // next tile resident / buffer free
    }
}

// ---------------- accum: wave/node, lane=feat, register-meta + depth-8 prefetch ----------------
__global__ __launch_bounds__(256) void node_accum_kernel(
    const unsigned short* __restrict__ abf, const unsigned short* __restrict__ bsf,
    const float* __restrict__ W1, const float* __restrict__ W2, const float* __restrict__ b2,
    const int* __restrict__ offs, const int* __restrict__ counts,
    const int2* __restrict__ meta, float* __restrict__ out, int n_nodes)
{
    const int lane = threadIdx.x & 63;
    const int wv   = __builtin_amdgcn_readfirstlane(threadIdx.x >> 6);
    const int n    = blockIdx.x * 4 + wv;          // wave-uniform node id
    if (n >= n_nodes) return;

    const float basel = __uint_as_float((uint)bsf[(size_t)n * 64 + lane] << 16);
    const float w128l = W1[(size_t)128 * 64 + lane];
    float acc = 0.f;

    const int beg = offs[n];     // s_load (n uniform)
    const int np  = counts[n];   // s_load

    // chunks of <=64 edges: meta staged into registers by ONE lane-parallel load,
    // per-edge src/e extracted with v_readlane (no memory on the gather-addr path)
    for (int c0 = 0; c0 < np; c0 += 64) {
        const int cn = min(np - c0, 64);

        int mx = 0, my = 0;
        if (lane < cn) {
            const int2 m = meta[beg + c0 + lane];   // 512B coalesced, once per chunk
            mx = m.x; my = m.y;
        }

        // pipeline slots hold the RAW zext ushort; <<16 happens at consume time
        uint x0=0,x1=0,x2=0,x3=0,x4=0,x5=0,x6=0,x7=0;

        auto ld = [&](int j, uint& x) {
            const int s = __builtin_amdgcn_readlane(mx, j);        // uniform src id
            x = (uint)abf[(size_t)s * 64 + lane];                  // saddr gather, 128B/wave
        };
        auto step = [&](int j, uint xr) {
            const float ev = __uint_as_float((uint)__builtin_amdgcn_readlane(my, j));
            const float xv = __uint_as_float(xr << 16);
            acc += fmaxf(fmaf(ev, w128l, basel) + xv, 0.f);
        };

        if (cn > 0) ld(0, x0);
        if (cn > 1) ld(1, x1);
        if (cn > 2) ld(2, x2);
        if (cn > 3) ld(3, x3);
        if (cn > 4) ld(4, x4);
        if (cn > 5) ld(5, x5);
        if (cn > 6) ld(6, x6);
        if (cn > 7) ld(7, x7);

        int i = 0;
        while (i + 16 <= cn) {
            step(i + 0, x0); ld(i + 8,  x0);
            step(i + 1, x1); ld(i + 9,  x1);
            step(i + 2, x2); ld(i + 10, x2);
            step(i + 3, x3); ld(i + 11, x3);
            step(i + 4, x4); ld(i + 12, x4);
            step(i + 5, x5); ld(i + 13, x5);
            step(i + 6, x6); ld(i + 14, x6);
            step(i + 7, x7); ld(i + 15, x7);
            i += 8;
        }
        const int r = cn - i;   // 0..15
        if (r > 0)  { step(i + 0, x0); }  if (r > 8)  { ld(i + 8,  x0); }
        if (r > 1)  { step(i + 1, x1); }  if (r > 9)  { ld(i + 9,  x1); }
        if (r > 2)  { step(i + 2, x2); }  if (r > 10) { ld(i + 10, x2); }
        if (r > 3)  { step(i + 3, x3); }  if (r > 11) { ld(i + 11, x3); }
        if (r > 4)  { step(i + 4, x4); }  if (r > 12) { ld(i + 12, x4); }
        if (r > 5)  { step(i + 5, x5); }  if (r > 13) { ld(i + 13, x5); }
        if (r > 6)  { step(i + 6, x6); }  if (r > 14) { ld(i + 14, x6); }
        if (r > 7)  { step(i + 7, x7); }
        if (r > 8)  { step(i + 8,  x0); }
        if (r > 9)  { step(i + 9,  x1); }
        if (r > 10) { step(i + 10, x2); }
        if (r > 11) { step(i + 11, x3); }
        if (r > 12) { step(i + 12, x4); }
        if (r > 13) { step(i + 13, x5); }
        if (r > 14) { step(i + 14, x6); }
    }

    // fused epilogue: out[n][lane] = sum_j acc_j * W2[j][lane] + np*b2[lane]
    float o = (float)np * b2[lane];
    #pragma unroll
    for (int j = 0; j < 64; ++j) {
        const float aj = __shfl(acc, j, 64);               // v_readlane
        o = fmaf(aj, W2[(size_t)j * 64 + lane], o);        // coalesced, L1-hot
    }
    out[(size_t)n * 64 + lane] = o;
}

extern "C" void kernel_launch(void* const* d_in, const int* in_sizes, int n_in,
                              void* d_out, int out_size, void* d_ws, size_t ws_size,
                              hipStream_t stream) {
    const float* h  = (const float*)d_in[0];
    const float* e  = (const float*)d_in[1];
    const int* src  = (const int*)d_in[2];
    const int* dst  = (const int*)d_in[3];
    const float* W1 = (const float*)d_in[4];
    const float* b1 = (const float*)d_in[5];
    const float* W2 = (const float*)d_in[6];
    const float* b2 = (const float*)d_in[7];
    float* out = (float*)d_out;

    const int n_edges = in_sizes[2];
    const int N = in_sizes[0] / 64;

    // shard size: multiple of 256 so every 256-node block sits in one shard
    const int shsz = ((N + NSH * 256 - 1) / (NSH * 256)) * 256;   // 12544 for N=100000

    // ws: [counts N | shardTotal 8 | shard_cursor 8 | offs N | rank E] ints,
    //     [meta 2E] ints, [abf 64N ushort], [bsf 64N ushort]
    int* counts       = (int*)d_ws;
    int* shardTotal   = counts + N;
    int* shard_cursor = shardTotal + NSH;
    int* offs         = shard_cursor + NSH;
    int* rank         = offs + N;
    int2* meta        = (int2*)(rank + n_edges);
    unsigned short* abf = (unsigned short*)(meta + n_edges);
    unsigned short* bsf = abf + (size_t)64 * N;

    // zero all atomically-updated counters every call (counts + shard totals/cursors)
    hipMemsetAsync(counts, 0, ((size_t)N + 2 * NSH) * sizeof(int), stream);

    const int eb = (n_edges + 255) / 256;
    const int nb = (N + 255) / 256;
    const int pg = (N + PRE_NPB - 1) / PRE_NPB;

    precompute_ab_kernel<<<pg, 256, 0, stream>>>(h, W1, b1, abf, bsf, N);
    count_kernel<<<eb, 256, 0, stream>>>(dst, counts, rank, n_edges);
    shard_sum_kernel<<<nb, 256, 0, stream>>>(counts, shardTotal, N, shsz);
    alloc_offs_kernel<<<nb, 256, 0, stream>>>(counts, shardTotal, shard_cursor, offs, N, shsz);
    fill_kernel<<<eb, 256, 0, stream>>>(dst, src, e, offs, rank, meta, n_edges);
    node_accum_kernel<<<(N + 3) / 4, 256, 0, stream>>>(abf, bsf, W1, W2, b2,
                                                       offs, counts, meta, out, N);
}